// Round 5
// baseline (240.318 us; speedup 1.0000x reference)
//
#include <hip/hip_runtime.h>

#define NL 30

typedef float f2 __attribute__((ext_vector_type(2)));  // clang vector: OK for nontemporal builtins

// Persistent, software-pipelined streaming kernel.
// 2 rows/thread per tile; each thread processes `niters` tiles spaced
// `stride_rows` apart. Next tile's loads are issued before current tile's
// 30-layer compute, so vmem latency hides behind ~2000 cyc of VALU work.
__global__ __launch_bounds__(256, 8) void drn_kernel(
    const float* __restrict__ x1, const float* __restrict__ x2,
    const float* __restrict__ W1, const float* __restrict__ b1,
    const float* __restrict__ W2,
    float* __restrict__ o1, float* __restrict__ o2,
    int niters, long stride_rows)
{
    long row = ((long)blockIdx.x * blockDim.x + threadIdx.x) * 2;

    // Prefetch tile 0: x1 -> 1 f2; x2 rows [2t,2t+2) = 10 floats -> 5 f2.
    // All 8-B aligned (offsets are multiples of 8 B).
    f2 c1 = __builtin_nontemporal_load((const f2*)(x1 + row));
    f2 c2[5];
    {
        const f2* p = (const f2*)(x2 + row * 5);
        #pragma unroll
        for (int j = 0; j < 5; ++j) c2[j] = __builtin_nontemporal_load(p + j);
    }

    for (int it = 0; it < niters; ++it) {
        long nrow = row + stride_rows;
        f2 n1, n2[5];
        bool has_next = (it + 1 < niters);     // wave-uniform branch
        if (has_next) {
            n1 = __builtin_nontemporal_load((const f2*)(x1 + nrow));
            const f2* p = (const f2*)(x2 + nrow * 5);
            #pragma unroll
            for (int j = 0; j < 5; ++j) n2[j] = __builtin_nontemporal_load(p + j);
        }

        // Unpack current tile (pure register renaming, no movs).
        float h1a = c1.x, h1b = c1.y;
        float r0[5] = {c2[0].x, c2[0].y, c2[1].x, c2[1].y, c2[2].x};
        float r1[5] = {c2[2].y, c2[3].x, c2[3].y, c2[4].x, c2[4].y};

        #pragma unroll
        for (int l = 0; l < NL; ++l) {
            // Wave-uniform readonly -> s_load; SGPR operands feed v_fma directly.
            float w10 = W1[l * 5 + 0], w11 = W1[l * 5 + 1], w12 = W1[l * 5 + 2],
                  w13 = W1[l * 5 + 3], w14 = W1[l * 5 + 4];
            float bb  = b1[l];
            float w20 = W2[l * 5 + 0], w21 = W2[l * 5 + 1], w22 = W2[l * 5 + 2],
                  w23 = W2[l * 5 + 3], w24 = W2[l * 5 + 4];

            // Row a
            float s = h1a + bb;
            s = fmaf(fmaxf(r0[0], 0.f), w10, s);
            s = fmaf(fmaxf(r0[1], 0.f), w11, s);
            s = fmaf(fmaxf(r0[2], 0.f), w12, s);
            s = fmaf(fmaxf(r0[3], 0.f), w13, s);
            s = fmaf(fmaxf(r0[4], 0.f), w14, s);
            h1a = s;
            float rh = fmaxf(s, 0.f);
            r0[0] = fmaf(rh, w20, r0[0]);
            r0[1] = fmaf(rh, w21, r0[1]);
            r0[2] = fmaf(rh, w22, r0[2]);
            r0[3] = fmaf(rh, w23, r0[3]);
            r0[4] = fmaf(rh, w24, r0[4]);

            // Row b
            float u = h1b + bb;
            u = fmaf(fmaxf(r1[0], 0.f), w10, u);
            u = fmaf(fmaxf(r1[1], 0.f), w11, u);
            u = fmaf(fmaxf(r1[2], 0.f), w12, u);
            u = fmaf(fmaxf(r1[3], 0.f), w13, u);
            u = fmaf(fmaxf(r1[4], 0.f), w14, u);
            h1b = u;
            float sh = fmaxf(u, 0.f);
            r1[0] = fmaf(sh, w20, r1[0]);
            r1[1] = fmaf(sh, w21, r1[1]);
            r1[2] = fmaf(sh, w22, r1[2]);
            r1[3] = fmaf(sh, w23, r1[3]);
            r1[4] = fmaf(sh, w24, r1[4]);
        }

        // Store current tile (same packing as the loads).
        __builtin_nontemporal_store((f2){h1a, h1b}, (f2*)(o1 + row));
        {
            f2* p = (f2*)(o2 + row * 5);
            __builtin_nontemporal_store((f2){r0[0], r0[1]}, p + 0);
            __builtin_nontemporal_store((f2){r0[2], r0[3]}, p + 1);
            __builtin_nontemporal_store((f2){r0[4], r1[0]}, p + 2);
            __builtin_nontemporal_store((f2){r1[1], r1[2]}, p + 3);
            __builtin_nontemporal_store((f2){r1[3], r1[4]}, p + 4);
        }

        // Rotate the pipeline.
        if (has_next) {
            c1 = n1;
            #pragma unroll
            for (int j = 0; j < 5; ++j) c2[j] = n2[j];
        }
        row = nrow;
    }
}

extern "C" void kernel_launch(void* const* d_in, const int* in_sizes, int n_in,
                              void* d_out, int out_size, void* d_ws, size_t ws_size,
                              hipStream_t stream) {
    const float* x1 = (const float*)d_in[0];
    const float* x2 = (const float*)d_in[1];
    const float* W1 = (const float*)d_in[2];
    const float* b1 = (const float*)d_in[3];
    const float* W2 = (const float*)d_in[4];
    int nrows = in_sizes[0];            // 4,194,304
    float* o1 = (float*)d_out;          // [nrows]
    float* o2 = (float*)d_out + nrows;  // [nrows*5]

    const int block = 256;
    const int grid = 2048;              // 8 blocks/CU over 256 CUs
    long stride_rows = (long)grid * block * 2;          // rows per grid pass
    int niters = (int)((nrows + stride_rows - 1) / stride_rows);  // = 4

    drn_kernel<<<grid, block, 0, stream>>>(x1, x2, W1, b1, W2, o1, o2,
                                           niters, stride_rows);
}

// Round 6
// 193.335 us; speedup vs baseline: 1.2430x; 1.2430x over previous
//
#include <hip/hip_runtime.h>

#define NL 30

// One row per thread: maximal TLP (65,536 waves), minimal per-wave serial work.
// Params staged once per block into LDS (12 floats/layer, 48B stride, 16B
// aligned -> 3x ds_read_b128 broadcast per layer, conflict-free).
__global__ __launch_bounds__(256) void drn_kernel(
    const float* __restrict__ x1, const float* __restrict__ x2,
    const float* __restrict__ W1, const float* __restrict__ b1,
    const float* __restrict__ W2,
    float* __restrict__ o1, float* __restrict__ o2)
{
    __shared__ __align__(16) float sp[NL * 12];
    for (int i = threadIdx.x; i < NL * 12; i += 256) {
        int l = i / 12, k = i % 12;
        float v = 0.0f;
        if (k < 5)        v = W1[l * 5 + k];
        else if (k == 5)  v = b1[l];
        else if (k < 11)  v = W2[l * 5 + (k - 6)];
        sp[i] = v;
    }
    __syncthreads();

    int row = blockIdx.x * 256 + threadIdx.x;

    // 32-bit offsets -> global_load_dword v, voffset, s[base] addressing.
    float h1 = x1[row];
    int b = row * 5;
    float h2[5];
    #pragma unroll
    for (int j = 0; j < 5; ++j) h2[j] = x2[b + j];

    for (int l = 0; l < NL; ++l) {
        float4 p0 = *(const float4*)&sp[l * 12];
        float4 p1 = *(const float4*)&sp[l * 12 + 4];
        float4 p2 = *(const float4*)&sp[l * 12 + 8];
        // w1 = {p0.x,p0.y,p0.z,p0.w,p1.x}, b = p1.y, w2 = {p1.z,p1.w,p2.x,p2.y,p2.z}
        float s = h1 + p1.y;
        s = fmaf(fmaxf(h2[0], 0.f), p0.x, s);
        s = fmaf(fmaxf(h2[1], 0.f), p0.y, s);
        s = fmaf(fmaxf(h2[2], 0.f), p0.z, s);
        s = fmaf(fmaxf(h2[3], 0.f), p0.w, s);
        s = fmaf(fmaxf(h2[4], 0.f), p1.x, s);
        h1 = s;
        float rh = fmaxf(s, 0.f);
        h2[0] = fmaf(rh, p1.z, h2[0]);
        h2[1] = fmaf(rh, p1.w, h2[1]);
        h2[2] = fmaf(rh, p2.x, h2[2]);
        h2[3] = fmaf(rh, p2.y, h2[3]);
        h2[4] = fmaf(rh, p2.z, h2[4]);
    }

    o1[row] = h1;
    #pragma unroll
    for (int j = 0; j < 5; ++j) o2[b + j] = h2[j];
}

extern "C" void kernel_launch(void* const* d_in, const int* in_sizes, int n_in,
                              void* d_out, int out_size, void* d_ws, size_t ws_size,
                              hipStream_t stream) {
    const float* x1 = (const float*)d_in[0];
    const float* x2 = (const float*)d_in[1];
    const float* W1 = (const float*)d_in[2];
    const float* b1 = (const float*)d_in[3];
    const float* W2 = (const float*)d_in[4];
    int nrows = in_sizes[0];            // 4,194,304
    float* o1 = (float*)d_out;          // [nrows]
    float* o2 = (float*)d_out + nrows;  // [nrows*5]

    int block = 256;
    int grid = nrows / block;           // 16384 blocks, 1 row/thread
    drn_kernel<<<grid, block, 0, stream>>>(x1, x2, W1, b1, W2, o1, o2);
}